// Round 2
// baseline (997.397 us; speedup 1.0000x reference)
//
#include <hip/hip_runtime.h>
#include <hip/hip_bf16.h>
#include <stdint.h>

// Problem constants (fixed by reference)
#define BATCH 16
#define NPTS  8192
#define NCH   6
#define NGRP  512   // NUM_GROUPS (FPS samples)
#define GSZ   32    // GROUP_SIZE (kNN)

// ---------------------------------------------------------------------------
// Kernel 1: farthest point sampling. One block per batch, 1024 threads,
// 8 points per thread held in registers. Writes centers [B][NGRP][3] directly
// into the output buffer.
//
// Numerics: must be BIT-IDENTICAL to the numpy reference so that argmax
// selections match exactly. The reference computes (xyz-last)**2 and the
// 3-sum as SEPARATE array passes -> no FMA contraction possible there, plain
// left-to-right adds: d = (dx*dx + dy*dy) + dz*dz with fp contract off.
// Tie-break: np.argmax returns the FIRST max index -> pack
// key = (bits(min_d)<<32) | (0xFFFFFFFF - idx), take max (min_d >= 0 so the
// f32 bit pattern is monotone).
// ---------------------------------------------------------------------------
__global__ __launch_bounds__(1024) void fps_kernel(
    const float* __restrict__ points, float* __restrict__ centers) {
#pragma clang fp contract(off)
  const int b    = blockIdx.x;
  const int tid  = threadIdx.x;
  const int lane = tid & 63;
  const int wave = tid >> 6;
  const float* P = points + (size_t)b * NPTS * NCH;

  float px[8], py[8], pz[8], md[8];
  for (int j = 0; j < 8; ++j) {
    const int i = j * 1024 + tid;
    px[j] = P[i * 6 + 0];
    py[j] = P[i * 6 + 1];
    pz[j] = P[i * 6 + 2];
    md[j] = __builtin_inff();
  }

  __shared__ unsigned long long wmax[2][16];  // double-buffered wave leaders

  int last = 0;
  for (int k = 0; k < NGRP; ++k) {
    // broadcast-load the current farthest point (uniform address, L1 hit)
    const float lx = P[last * 6 + 0];
    const float ly = P[last * 6 + 1];
    const float lz = P[last * 6 + 2];
    if (tid == 0) {
      float* c = centers + ((size_t)b * NGRP + k) * 3;
      c[0] = lx; c[1] = ly; c[2] = lz;
    }

    unsigned long long best = 0ull;
    for (int j = 0; j < 8; ++j) {
      const float dx = px[j] - lx;
      const float dy = py[j] - ly;
      const float dz = pz[j] - lz;
      const float d  = (dx * dx + dy * dy) + dz * dz;  // ref op order, no fma
      md[j] = fminf(md[j], d);
      const unsigned long long key =
          ((unsigned long long)__float_as_uint(md[j]) << 32) |
          (unsigned long long)(0xFFFFFFFFu - (unsigned)(j * 1024 + tid));
      best = best > key ? best : key;
    }
    // wave (64-lane) max reduce
    for (int off = 32; off >= 1; off >>= 1) {
      const unsigned long long o = __shfl_down(best, off);
      best = best > o ? best : o;
    }
    if (lane == 0) wmax[k & 1][wave] = best;
    __syncthreads();
    // every thread redundantly reduces the 16 wave leaders (broadcast reads)
    unsigned long long w = wmax[k & 1][0];
    for (int q = 1; q < 16; ++q) {
      const unsigned long long o = wmax[k & 1][q];
      w = w > o ? w : o;
    }
    last = (int)(0xFFFFFFFFu - (unsigned)(w & 0xFFFFFFFFull));
  }
}

// ---------------------------------------------------------------------------
// Kernel 2: 32-NN per (batch, group) + gather + center-relative output.
// One 256-thread block per group; each thread owns 32 candidate keys in
// registers and a cached local min. 32 rounds of block-wide u64 min-reduce;
// only the winning index's owner thread rescans/rebuilds its local min.
//
// d2 matches the reference expansion:
//   d2 = (cc - 2*dot) + xx
// cc and xx are separate mul-then-sum array passes in the reference -> plain
// left-to-right adds, no FMA. dot comes from einsum/dot_general whose inner
// contraction loop IS fma-contracted (numpy einsum scalar loop under gcc
// -ffp-contract=fast / Eigen AVX2 vfmadd), K ascending:
//   dot = fma(cz, z, fma(cy, y, cx*x))      <-- ROUND 2 CHANGE
// (fma(cx,x,0) == cx*x exactly, so the first link is a plain product.)
// d2 may be slightly negative in fp -> standard sortable-uint map.
// Tie-break: key low word = idx, ascending -> lower index first (lax.top_k).
// ---------------------------------------------------------------------------
__global__ __launch_bounds__(256) void knn_kernel(
    const float* __restrict__ points, const float* __restrict__ centers,
    float* __restrict__ grouped) {
#pragma clang fp contract(off)
  const int g    = blockIdx.x;
  const int b    = blockIdx.y;
  const int tid  = threadIdx.x;
  const int lane = tid & 63;
  const int wave = tid >> 6;
  const float* P   = points + (size_t)b * NPTS * NCH;
  const float* cen = centers + ((size_t)b * NGRP + g) * 3;
  const float cx = cen[0], cy = cen[1], cz = cen[2];
  const float cc = (cx * cx + cy * cy) + cz * cz;

  unsigned long long keys[32];
  for (int j = 0; j < 32; ++j) {
    const int i = j * 256 + tid;
    const float x = P[i * 6 + 0];
    const float y = P[i * 6 + 1];
    const float z = P[i * 6 + 2];
    const float xx  = (x * x + y * y) + z * z;
    const float dot = fmaf(cz, z, fmaf(cy, y, cx * x));  // fma chain, see above
    const float d2  = (cc - 2.0f * dot) + xx;
    unsigned u = __float_as_uint(d2);
    u = (u & 0x80000000u) ? ~u : (u | 0x80000000u);  // sortable map (d2 can be <0)
    keys[j] = ((unsigned long long)u << 32) | (unsigned long long)(unsigned)i;
  }
  unsigned long long lmin = keys[0];
  for (int j = 1; j < 32; ++j) lmin = lmin < keys[j] ? lmin : keys[j];

  __shared__ unsigned long long wred[2][4];
  __shared__ int knn_sh[GSZ];

  for (int j = 0; j < GSZ; ++j) {
    unsigned long long v = lmin;
    for (int off = 32; off >= 1; off >>= 1) {
      const unsigned long long o = __shfl_down(v, off);
      v = v < o ? v : o;
    }
    if (lane == 0) wred[j & 1][wave] = v;
    __syncthreads();
    unsigned long long w = wred[j & 1][0];
    for (int q = 1; q < 4; ++q) {
      const unsigned long long o = wred[j & 1][q];
      w = w < o ? w : o;
    }
    const int widx = (int)(unsigned)(w & 0xFFFFFFFFull);
    if (tid == (widx & 255)) {  // owner removes the winner, rebuilds local min
      for (int s = 0; s < 32; ++s)
        if ((unsigned)(keys[s] & 0xFFFFFFFFull) == (unsigned)widx)
          keys[s] = ~0ull;
      lmin = keys[0];
      for (int s = 1; s < 32; ++s) lmin = lmin < keys[s] ? lmin : keys[s];
    }
    if (tid == 0) knn_sh[j] = widx;
  }
  __syncthreads();

  // gather + center-relative xyz; 192 output floats per group
  float* outg = grouped + ((size_t)b * NGRP + g) * GSZ * NCH;
  for (int t = tid; t < GSZ * NCH; t += 256) {
    const int n = t / 6, c = t % 6;
    const int idx = knn_sh[n];
    float v = P[idx * 6 + c];
    if (c < 3) v = v - cen[c];  // grouped[...,:3] - centers, exact ref subtract
    outg[t] = v;
  }
}

extern "C" void kernel_launch(void* const* d_in, const int* in_sizes, int n_in,
                              void* d_out, int out_size, void* d_ws, size_t ws_size,
                              hipStream_t stream) {
  const float* points = (const float*)d_in[0];
  float* out = (float*)d_out;
  float* grouped = out;                                        // [16,512,32,6]
  float* centers = out + (size_t)BATCH * NGRP * GSZ * NCH;     // [16,512,3]

  fps_kernel<<<BATCH, 1024, 0, stream>>>(points, centers);
  knn_kernel<<<dim3(NGRP, BATCH), 256, 0, stream>>>(points, centers, grouped);
}